// Round 1
// baseline (1184.795 us; speedup 1.0000x reference)
//
#include <hip/hip_runtime.h>

// SS2D / VMamba block. b=256, 16x16 spatial, d=64, N=24, dt_rank=24, K=4.
// WS layout (floats): z[4.19M] | x[4.19M] | xq(=y_acc alias)[4.19M] | xdbl[18.87M]
// total = 125,829,120 bytes.

#define NST 24
#define RNK 24

__device__ __forceinline__ float siluf_(float x){ return x / (1.0f + __expf(-x)); }
__device__ __forceinline__ float softplusf_(float x){ return x > 20.0f ? x : log1pf(__expf(x)); }

// direction index map: src and combine-dst are the same permutation per k
__device__ __forceinline__ int srcidx(int k, int l){
    int lk = (k & 2) ? (255 - l) : l;
    if (k & 1) lk = ((lk & 15) << 4) | (lk >> 4);
    return lk;
}

// ---------------- K1: z = silu(x_in @ Wz^T), per-row 64x64 matvec ----------------
__global__ void k_zproj(const float* __restrict__ x_in, const float* __restrict__ w,
                        float* __restrict__ z){
    __shared__ float wl[64 * 65];
    int b = blockIdx.x;
    for (int i = threadIdx.x; i < 4096; i += 256) wl[(i >> 6) * 65 + (i & 63)] = w[i];
    __syncthreads();
    int wid = threadIdx.x >> 6, lane = threadIdx.x & 63;
    for (int r = wid; r < 256; r += 4){
        float xd = x_in[(b * 256 + r) * 64 + lane];
        float acc = 0.f;
        #pragma unroll
        for (int d = 0; d < 64; ++d) acc += __shfl(xd, d, 64) * wl[lane * 65 + d];
        z[(b * 256 + r) * 64 + lane] = siluf_(acc);
    }
}

// ---------------- K2: rearrange + depthwise 3x3 conv + silu -> xq[b][a][H][W] ----
__global__ void k_dwconv(const float* __restrict__ x_in, const float* __restrict__ cw,
                         const float* __restrict__ cb, float* __restrict__ xq){
    int idx = blockIdx.x * 256 + threadIdx.x;
    int W = idx & 63, H = (idx >> 6) & 63, a = (idx >> 12) & 3, b = idx >> 14;
    float acc = cb[a];
    #pragma unroll
    for (int dh = 0; dh < 3; ++dh){
        int Hs = H + dh - 1;
        if ((unsigned)Hs < 64u){
            #pragma unroll
            for (int dw = 0; dw < 3; ++dw){
                int Ws = W + dw - 1;
                if ((unsigned)Ws < 64u){
                    // image(a,H,W) = x_in[b, H/4, W/4, a*16 + (H%4)*4 + (W%4)]
                    int d = a * 16 + (Hs & 3) * 4 + (Ws & 3);
                    float v = x_in[(((b * 16) + (Hs >> 2)) * 16 + (Ws >> 2)) * 64 + d];
                    acc += v * cw[a * 9 + dh * 3 + dw];
                }
            }
        }
    }
    xq[idx] = siluf_(acc);
}

// ---------------- K3: 4x4 stride-4 patch conv + bias + BN -> x[b][l][e] ----------
__global__ void k_patch(const float* __restrict__ xq, const float* __restrict__ pw,
                        const float* __restrict__ pb,
                        const float* __restrict__ g, const float* __restrict__ be,
                        const float* __restrict__ mu, const float* __restrict__ var,
                        float* __restrict__ x){
    int idx = blockIdx.x * 256 + threadIdx.x;
    int e = idx & 63, l = (idx >> 6) & 255, b = idx >> 14;
    int p = l >> 4, q = l & 15;
    float acc = 0.f;
    #pragma unroll
    for (int a = 0; a < 4; ++a){
        #pragma unroll
        for (int i = 0; i < 4; ++i){
            const float* row = xq + (((b * 4 + a) * 64) + (p * 4 + i)) * 64 + q * 4;
            #pragma unroll
            for (int j = 0; j < 4; ++j) acc += row[j] * pw[((e * 4 + a) * 4 + i) * 4 + j];
        }
    }
    acc += pb[e];
    acc = (acc - mu[e]) * rsqrtf(var[e] + 1e-5f);
    acc = acc * g[e] + be[e];
    x[(b * 256 + l) * 64 + e] = acc;
}

// ---------------- K4: x_dbl[b][k][l][c] = sum_d xs[k][d][l] * Wx[k][c][d] --------
__global__ void k_xdbl(const float* __restrict__ x, const float* __restrict__ xw,
                       float* __restrict__ xdbl){
    __shared__ float wl[72 * 65];
    int idx0 = blockIdx.x * 4;
    int k = (idx0 >> 8) & 3;            // same k for all 4 waves in a block
    for (int i = threadIdx.x; i < 72 * 64; i += 256)
        wl[(i >> 6) * 65 + (i & 63)] = xw[k * 72 * 64 + i];
    __syncthreads();
    int wid = threadIdx.x >> 6, lane = threadIdx.x & 63;
    int idx = idx0 + wid;
    int l = idx & 255, b = idx >> 10;
    int s = srcidx(k, l);
    float xd = x[(b * 256 + s) * 64 + lane];
    float acc0 = 0.f, acc1 = 0.f;
    int c1 = 64 + (lane & 7);
    #pragma unroll
    for (int d = 0; d < 64; ++d){
        float xv = __shfl(xd, d, 64);
        acc0 += xv * wl[lane * 65 + d];
        acc1 += xv * wl[c1 * 65 + d];
    }
    float* o = xdbl + ((b * 4 + k) * 256 + l) * 72;
    o[lane] = acc0;
    if (lane < 8) o[c1] = acc1;
}

// ---------------- K5: selective scan, block=(b,k), lane=d ------------------------
__global__ void k_scan(const float* __restrict__ x, const float* __restrict__ xdbl,
                       const float* __restrict__ Alogs, const float* __restrict__ dtw_g,
                       const float* __restrict__ dtb, const float* __restrict__ Dsg,
                       float* __restrict__ yacc){
    int b = blockIdx.x >> 2, k = blockIdx.x & 3, d = threadIdx.x;
    int kd = k * 64 + d;
    float A[NST], dtw[RNK], h[NST];
    #pragma unroll
    for (int n = 0; n < NST; ++n){ A[n] = -__expf(Alogs[kd * 24 + n]); h[n] = 0.f; }
    #pragma unroll
    for (int r = 0; r < RNK; ++r) dtw[r] = dtw_g[kd * 24 + r];
    float Dv = Dsg[kd], bias = dtb[kd];
    const float* pb = xdbl + ((size_t)(b * 4 + k) * 256) * 72;
    const float* xb = x + (size_t)b * 256 * 64;
    float* yb = yacc + (size_t)b * 256 * 64;
    for (int l = 0; l < 256; ++l){
        const float* p = pb + l * 72;
        float acc = bias;
        #pragma unroll
        for (int r = 0; r < RNK; ++r) acc += p[r] * dtw[r];     // wave-uniform broadcast loads
        float delta = softplusf_(acc);
        int s = srcidx(k, l);
        float u = xb[s * 64 + d];
        float du = delta * u;
        float y = Dv * u;
        #pragma unroll
        for (int n = 0; n < NST; ++n){
            float dA = __expf(delta * A[n]);
            h[n] = dA * h[n] + du * p[24 + n];
            y += h[n] * p[48 + n];
        }
        atomicAdd(yb + s * 64 + d, y);   // src perm == combine perm per direction
    }
}

// ---------------- K6: LN(64) + gate with z + out_proj ----------------------------
__global__ void k_final(const float* __restrict__ yacc, const float* __restrict__ z,
                        const float* __restrict__ lg, const float* __restrict__ lb,
                        const float* __restrict__ wo, float* __restrict__ out){
    __shared__ float wl[64 * 65];
    for (int i = threadIdx.x; i < 4096; i += 256) wl[(i >> 6) * 65 + (i & 63)] = wo[i];
    __syncthreads();
    int wid = threadIdx.x >> 6, lane = threadIdx.x & 63;
    int idx = blockIdx.x * 4 + wid;       // (b*256 + l)
    int off = idx * 64;
    float yv = yacc[off + lane];
    float ssum = yv;
    #pragma unroll
    for (int m = 32; m >= 1; m >>= 1) ssum += __shfl_xor(ssum, m, 64);
    float mean = ssum * (1.0f / 64.0f);
    float t = yv - mean;
    float v = t * t;
    #pragma unroll
    for (int m = 32; m >= 1; m >>= 1) v += __shfl_xor(v, m, 64);
    float inv = rsqrtf(v * (1.0f / 64.0f) + 1e-5f);
    float yz = (t * inv * lg[lane] + lb[lane]) * z[off + lane];
    float acc = 0.f;
    #pragma unroll
    for (int e = 0; e < 64; ++e) acc += __shfl(yz, e, 64) * wl[lane * 65 + e];
    out[off + lane] = acc;
}

extern "C" void kernel_launch(void* const* d_in, const int* in_sizes, int n_in,
                              void* d_out, int out_size, void* d_ws, size_t ws_size,
                              hipStream_t stream){
    const float* x_in     = (const float*)d_in[0];
    const float* in_proj_w= (const float*)d_in[1];
    const float* conv_w   = (const float*)d_in[2];
    const float* conv_b   = (const float*)d_in[3];
    const float* patch_w  = (const float*)d_in[4];
    const float* patch_b  = (const float*)d_in[5];
    const float* bn_g     = (const float*)d_in[6];
    const float* bn_b     = (const float*)d_in[7];
    const float* bn_m     = (const float*)d_in[8];
    const float* bn_v     = (const float*)d_in[9];
    const float* x_proj_w = (const float*)d_in[10];
    const float* dt_w     = (const float*)d_in[11];
    const float* dt_b     = (const float*)d_in[12];
    const float* A_logs   = (const float*)d_in[13];
    const float* Dsg      = (const float*)d_in[14];
    const float* ln_g     = (const float*)d_in[15];
    const float* ln_b     = (const float*)d_in[16];
    const float* out_w    = (const float*)d_in[17];
    float* out = (float*)d_out;

    float* ws   = (float*)d_ws;
    float* z    = ws;                 // 4,194,304 floats
    float* x    = ws + 4194304;       // 4,194,304 floats
    float* xq   = ws + 8388608;       // 4,194,304 floats (dead after K3 -> reused as y_acc)
    float* xdbl = ws + 12582912;      // 18,874,368 floats
    float* yacc = xq;

    k_zproj <<<256,   256, 0, stream>>>(x_in, in_proj_w, z);
    k_dwconv<<<16384, 256, 0, stream>>>(x_in, conv_w, conv_b, xq);
    k_patch <<<16384, 256, 0, stream>>>(xq, patch_w, patch_b, bn_g, bn_b, bn_m, bn_v, x);
    hipMemsetAsync(yacc, 0, (size_t)4194304 * sizeof(float), stream);
    k_xdbl  <<<65536, 256, 0, stream>>>(x, x_proj_w, xdbl);
    k_scan  <<<1024,   64, 0, stream>>>(x, xdbl, A_logs, dt_w, dt_b, Dsg, yacc);
    k_final <<<16384, 256, 0, stream>>>(yacc, z, ln_g, ln_b, out_w, out);
}